// Round 16
// baseline (1121.972 us; speedup 1.0000x reference)
//
#include <hip/hip_runtime.h>
#include <math.h>

#define PPRI 192
#define NB   32
#define NS   36
#define BP   6144   // NB*PPRI
#define NPIX 250
#define FPI  3.14159265358979323846f

typedef _Float16 f16x8 __attribute__((ext_vector_type(8)));
typedef float f32x4  __attribute__((ext_vector_type(4)));

__device__ inline short f2h(float x) {
    _Float16 h = (_Float16)x;
    return *(short*)&h;
}
__device__ inline float h2f(short s) {
    _Float16 h = *(_Float16*)&s;
    return (float)h;
}
__device__ inline void splith(float x, short& h, short& l) {
    h = f2h(x); l = f2h(x - h2f(h));
}

// ---------------- init: pofm, p234, fc weights fp16 hi/lo, conv weights fp16 hi/lo,
//                   transposed head weights (coalesced [c][o] layouts) ----------------
__global__ void k_init(float* __restrict__ pofm, float* __restrict__ p234,
                       short* __restrict__ fcBh, short* __restrict__ fcBl,
                       const float* __restrict__ fc_w, const float* __restrict__ protos,
                       short* __restrict__ rgWh, short* __restrict__ rgWl,
                       const float* __restrict__ rg_w,
                       short* __restrict__ catWh, short* __restrict__ catWl,
                       const float* __restrict__ cw0, const float* __restrict__ cw1,
                       const float* __restrict__ cw2,
                       float* __restrict__ hT, float* __restrict__ rhwT,
                       float* __restrict__ chwT, float* __restrict__ ahwT,
                       float* __restrict__ protoNT,
                       const float* __restrict__ reg_w1, const float* __restrict__ reg_w2,
                       const float* __restrict__ cls_w1, const float* __restrict__ cls_w2,
                       const float* __restrict__ cat_w1, const float* __restrict__ cat_w2,
                       const float* __restrict__ attr_w1, const float* __restrict__ attr_w2,
                       const float* __restrict__ reg_head_w, const float* __restrict__ cls_head_w,
                       const float* __restrict__ attr_head_w) {
    int i = blockIdx.x * 256 + threadIdx.x;
    if (i < BP * NS) {
        int p = (i / NS) % PPRI;
        pofm[i] = ((float)p + 0.5f) / 192.0f;
    }
    if (i < BP) {
        p234[3*i+0] = 0.5f; p234[3*i+1] = 0.1f; p234[3*i+2] = 0.0f;
    }
    if (i < 64 * 2304) {           // fcB[o][k], k = s*64+oc  <- fc_w[o][oc*36+s]
        int o = i / 2304, k = i % 2304;
        int s = k >> 6, oc = k & 63;
        short h, l; splith(fc_w[o * 2304 + oc * 36 + s], h, l);
        fcBh[i] = h; fcBl[i] = l;
    }
    if (i < 82944) {               // rgW[st][k][oc][ic] <- rg_w[st][oc][ic][k]
        int st = i / 27648, r = i % 27648;
        int k = r / 3072, r2 = r % 3072;
        int oc = r2 / 64, ic = r2 & 63;
        short h, l; splith(rg_w[((st*48 + oc)*64 + ic)*9 + k], h, l);
        rgWh[i] = h; rgWl[i] = l;
    }
    if (i < 184320) {              // catW[st][k][oc][icp], icw = {64,96,160}
        int st, base, icw; const float* w;
        if (i < 36864)      { st = 0; base = 0;     icw = 64;  w = cw0; }
        else if (i < 92160) { st = 1; base = 36864; icw = 96;  w = cw1; }
        else                { st = 2; base = 92160; icw = 160; w = cw2; }
        int r = i - base;
        int k = r / (64*icw), r2 = r % (64*icw);
        int oc = r2 / icw, icp = r2 % icw;
        int IC = 48 * (st + 1);
        float wv = (icp < IC) ? w[(oc*IC + icp)*9 + k] : 0.f;
        short h, l; splith(wv, h, l);
        catWh[i] = h; catWl[i] = l;
    }
    if (i < 32768) {               // 8 transposed 64x64 head matrices: hT[m][c][o] = W[o][c]
        int m = i >> 12, r2 = i & 4095, c = r2 >> 6, o = r2 & 63;
        const float* Ws[8] = {reg_w1, reg_w2, cls_w1, cls_w2, cat_w1, cat_w2, attr_w1, attr_w2};
        hT[i] = Ws[m][o*64 + c];
    }
    if (i < 76*64) {               // rhwT[c][o] = reg_head_w[o][c]
        int c = i / 76, o = i % 76;
        rhwT[c*76 + o] = reg_head_w[o*64 + c];
    }
    if (i < 128) {                 // chwT[c][o] = cls_head_w[o][c]
        int c = i >> 1, o = i & 1;
        chwT[c*2 + o] = cls_head_w[o*64 + c];
    }
    if (i < 256) {                 // ahwT[c][o] = attr_head_w[o][c]
        int c = i >> 2, o = i & 3;
        ahwT[c*4 + o] = attr_head_w[o*64 + c];
    }
    if (i < 960) {                 // protoNT[c][p] = protos[p][c]/||protos[p]||
        int c = i / 15, p = i % 15;
        float ss = 0.f;
        for (int j = 0; j < 64; ++j) { float v = protos[p*64 + j]; ss += v*v; }
        float nrm = fmaxf(sqrtf(ss), 1e-12f);
        protoNT[c*15 + p] = protos[p*64 + c] / nrm;
    }
}

// ---------------- feat transpose: [b][c][hw] -> featT[b][hw][c] (fp32, exact) ----------------
__global__ __launch_bounds__(256) void k_transpose(const float* __restrict__ in,
                                                   float* __restrict__ outT, int HW) {
    __shared__ float t[64][65];
    int b = blockIdx.y;
    int hw0 = blockIdx.x * 64;
    int tx = threadIdx.x & 63, ty = threadIdx.x >> 6;
    const float* ib = in + (size_t)b * 64 * HW;
    for (int c = ty; c < 64; c += 4) {
        int hw = hw0 + tx;
        t[c][tx] = (hw < HW) ? ib[(size_t)c * HW + hw] : 0.f;
    }
    __syncthreads();
    float* ob = outT + (size_t)b * HW * 64;
    for (int r = ty; r < 64; r += 4) {
        int hw = hw0 + r;
        if (hw < HW) ob[(size_t)hw * 64 + tx] = t[tx][r];
    }
}

// ---------------- FUSED per-stage: gridsample + rg conv (64->48) + cat conv (48*(st+1)->64) ----------------
// Region A: rg staging [hi|lo][37][RGWP]. Region B: cat staging [hi|lo][37][WP] (own-stage
// columns filled by rg epilogue in LDS). Region R: reduce scratch. All math identical to the
// split kernels; st<2 also writes rgC to global for later stages.
#define RGWP 80
template<int NC, int NT, int BW, int WP, int ICR, int OWN0, bool SPL, bool WRG>
__global__ __launch_bounds__(192) void k_rgcat(
        const float* __restrict__ featT, int H, int W,
        const float* __restrict__ pofm,
        const short* __restrict__ rWh, const short* __restrict__ rWl,
        const float* __restrict__ rsc, const float* __restrict__ rbi,
        const short* __restrict__ cWh, const short* __restrict__ cWl,
        const float* __restrict__ csc, const float* __restrict__ cbi,
        short* __restrict__ rgHout, short* __restrict__ rgLout,
        const short* __restrict__ Xh, const short* __restrict__ Xl,
        short* __restrict__ outH, short* __restrict__ outL) {
    constexpr int icw  = NC * 32;
    constexpr int CH   = icw / 8;
    constexpr int ARW  = (SPL ? 2 : 1) * 37 * RGWP;
    constexpr int BRW  = (SPL ? 2 : 1) * 37 * WP;
    constexpr int REDS = (3*NT*512 > 9*512) ? 3*NT*512 : 9*512;   // shorts
    __shared__ short smA[ARW];
    __shared__ short smB[BRW];
    __shared__ short smR[REDS];
    int tid = threadIdx.x;
    int row = blockIdx.x;
    int wv = tid >> 6, lane = tid & 63;
    int b = row / PPRI;
    // ---- phase 0a: bilinear sample into region A (lane = channel, coalesced) ----
    float myPof = (lane < 36) ? pofm[row * 36 + lane] : 0.f;
    const float* fb = featT + (size_t)b * H * W * 64;
    for (int si = 0; si < 12; ++si) {
        int s = wv * 12 + si;
        float px = __shfl(myPof, 35 - s);
        px = fminf(fmaxf(px, -1e6f), 1e6f);
        float pfy = (s == 0) ? 0.0f : ((float)(2*s+1) / 71.0f);
        float ix = px  * (float)(W - 1);
        float iy = pfy * (float)(H - 1);
        float x0f = floorf(ix), y0f = floorf(iy);
        float fx = ix - x0f, fy = iy - y0f;
        float vx0 = (x0f >= 0.f     && x0f     <= (float)(W-1)) ? 1.f : 0.f;
        float vx1 = (x0f+1.f >= 0.f && x0f+1.f <= (float)(W-1)) ? 1.f : 0.f;
        float vy0 = (y0f >= 0.f     && y0f     <= (float)(H-1)) ? 1.f : 0.f;
        float vy1 = (y0f+1.f >= 0.f && y0f+1.f <= (float)(H-1)) ? 1.f : 0.f;
        int x0 = min(max((int)x0f, 0), W-1);
        int x1 = min(max((int)x0f + 1, 0), W-1);
        int y0 = min(max((int)y0f, 0), H-1);
        int y1 = min(max((int)y0f + 1, 0), H-1);
        float w00 = (1.f-fx)*(1.f-fy)*vx0*vy0, w10 = fx*(1.f-fy)*vx1*vy0;
        float w01 = (1.f-fx)*fy*vx0*vy1,       w11 = fx*fy*vx1*vy1;
        float v = w00 * fb[(size_t)(y0*W+x0)*64 + lane]
                + w10 * fb[(size_t)(y0*W+x1)*64 + lane]
                + w01 * fb[(size_t)(y1*W+x0)*64 + lane]
                + w11 * fb[(size_t)(y1*W+x1)*64 + lane];
        int di = (s*RGWP + lane) ^ (((s >> 2) & 1) << 3);
        if (SPL) {
            short h, l; splith(v, h, l);
            smA[di] = h;
            smA[37*RGWP + di] = l;
        } else {
            smA[di] = f2h(v);
        }
    }
    if (wv == 0) {                 // zero sentinel row 36 of A
        int di = (36*RGWP + lane) ^ 8;
        smA[di] = 0;
        if (SPL) smA[37*RGWP + di] = 0;
    }
    // ---- phase 0b: cat staging into region B (earlier stages from global; own cols deferred) ----
    for (int idx = tid; idx < 37*CH; idx += 192) {
        int pos = idx / CH, c0 = (idx % CH) << 3;
        bool own = (c0 >= OWN0) && (c0 < OWN0 + 48);
        if (own && pos < 36) continue;         // filled by rg epilogue
        f16x8 h = {}, l = {};
        if (pos < 36 && c0 < ICR) {
            int sidx = c0 / BW, cc = c0 % BW;
            size_t src = ((size_t)(sidx*BP + row)*36 + pos)*BW + cc;
            h = *(const f16x8*)(Xh + src);
            if (SPL) l = *(const f16x8*)(Xl + src);
        }
        int di = (pos*WP + c0) ^ (((pos >> 2) & 1) << 3);
        *(f16x8*)(smB + di) = h;
        if (SPL) *(f16x8*)(smB + 37*WP + di) = l;
    }
    __syncthreads();
    int lr = lane & 15, kg = lane >> 4;
    // ================= rg conv (NC=2, NT=3) split-K, term-major =================
    {
        const short* shb = smA;
        const short* slb = smA + 37*RGWP;
        f32x4 acc[3][3] = {};
        #pragma unroll
        for (int ssh = 0; ssh < 3; ++ssh) {
            int sh = wv*3 + ssh;
            int sr0 = lr + sh - 4;
            int ar0 = ((unsigned)sr0 < 36u) ? sr0 : 36;
            int ar1 = 16 + lr + sh - 4;
            int sr2 = 32 + lr + sh - 4;
            int ar2 = ((unsigned)sr2 < 36u) ? sr2 : 36;
            int rb0 = ar0*RGWP, rs0 = ((ar0 >> 2) & 1) << 3;
            int rb1 = ar1*RGWP, rs1 = ((ar1 >> 2) & 1) << 3;
            int rb2 = ar2*RGWP, rs2 = ((ar2 >> 2) & 1) << 3;
            #pragma unroll
            for (int kc = 0; kc < 2; ++kc) {
                int icb = kc*32 + kg*8;
                int d0 = (rb0 + icb) ^ rs0;
                int d1 = (rb1 + icb) ^ rs1;
                int d2 = (rb2 + icb) ^ rs2;
                f16x8 ah[3] = { *(const f16x8*)(shb + d0), *(const f16x8*)(shb + d1),
                                *(const f16x8*)(shb + d2) };
                const short* wbh = rWh + (size_t)(sh*48)*64 + icb;
                f16x8 bh[3];
                #pragma unroll
                for (int nt = 0; nt < 3; ++nt) bh[nt] = *(const f16x8*)(wbh + (nt*16 + lr)*64);
                if (SPL) {
                    f16x8 al[3] = { *(const f16x8*)(slb + d0), *(const f16x8*)(slb + d1),
                                    *(const f16x8*)(slb + d2) };
                    const short* wbl = rWl + (size_t)(sh*48)*64 + icb;
                    f16x8 bl[3];
                    #pragma unroll
                    for (int nt = 0; nt < 3; ++nt) bl[nt] = *(const f16x8*)(wbl + (nt*16 + lr)*64);
                    #pragma unroll
                    for (int nt = 0; nt < 3; ++nt)
                        #pragma unroll
                        for (int mt = 0; mt < 3; ++mt)
                            acc[mt][nt] = __builtin_amdgcn_mfma_f32_16x16x32_f16(ah[mt], bh[nt], acc[mt][nt], 0,0,0);
                    #pragma unroll
                    for (int nt = 0; nt < 3; ++nt)
                        #pragma unroll
                        for (int mt = 0; mt < 3; ++mt)
                            acc[mt][nt] = __builtin_amdgcn_mfma_f32_16x16x32_f16(ah[mt], bl[nt], acc[mt][nt], 0,0,0);
                    #pragma unroll
                    for (int nt = 0; nt < 3; ++nt)
                        #pragma unroll
                        for (int mt = 0; mt < 3; ++mt)
                            acc[mt][nt] = __builtin_amdgcn_mfma_f32_16x16x32_f16(al[mt], bh[nt], acc[mt][nt], 0,0,0);
                } else {
                    #pragma unroll
                    for (int nt = 0; nt < 3; ++nt)
                        #pragma unroll
                        for (int mt = 0; mt < 3; ++mt)
                            acc[mt][nt] = __builtin_amdgcn_mfma_f32_16x16x32_f16(ah[mt], bh[nt], acc[mt][nt], 0,0,0);
                }
            }
        }
        __syncthreads();
        float* red = (float*)smR;
        if (wv == 2) {
            #pragma unroll
            for (int mt = 0; mt < 3; ++mt)
                #pragma unroll
                for (int nt = 0; nt < 3; ++nt)
                    *(f32x4*)(red + ((size_t)(mt*3 + nt))*256 + lane*4) = acc[mt][nt];
        }
        __syncthreads();
        if (wv == 1) {
            #pragma unroll
            for (int mt = 0; mt < 3; ++mt)
                #pragma unroll
                for (int nt = 0; nt < 3; ++nt) {
                    f32x4* p = (f32x4*)(red + ((size_t)(mt*3 + nt))*256 + lane*4);
                    *p = *p + acc[mt][nt];
                }
        }
        __syncthreads();
        if (wv == 0) {
            #pragma unroll
            for (int nt = 0; nt < 3; ++nt) {
                int oc = nt*16 + lr;
                float sc = rsc[oc], bi = rbi[oc];
                #pragma unroll
                for (int mt = 0; mt < 3; ++mt) {
                    f32x4 a = acc[mt][nt] + *(const f32x4*)(red + ((size_t)(mt*3 + nt))*256 + lane*4);
                    #pragma unroll
                    for (int i = 0; i < 4; ++i) {
                        int s = mt*16 + kg*4 + i;
                        if (s < 36) {
                            float v = fmaxf(a[i]*sc + bi, 0.f);
                            int di = (s*WP + OWN0 + oc) ^ (((s >> 2) & 1) << 3);
                            if (SPL) {
                                short h, l; splith(v, h, l);
                                smB[di] = h;
                                smB[37*WP + di] = l;
                                if (WRG) {
                                    rgHout[(size_t)row*36*48 + s*48 + oc] = h;
                                    rgLout[(size_t)row*36*48 + s*48 + oc] = l;
                                }
                            } else {
                                short h = f2h(v);
                                smB[di] = h;
                                if (WRG) rgHout[(size_t)row*36*48 + s*48 + oc] = h;
                            }
                        }
                    }
                }
            }
        }
    }
    __syncthreads();
    // ================= cat conv (NC, NT) split-K, term-major =================
    {
        const short* shb = smB;
        const short* slb = smB + 37*WP;
        f32x4 acc[3][NT] = {};
        #pragma unroll
        for (int ssh = 0; ssh < 3; ++ssh) {
            int sh = wv*3 + ssh;
            int sr0 = lr + sh - 4;
            int ar0 = ((unsigned)sr0 < 36u) ? sr0 : 36;
            int ar1 = 16 + lr + sh - 4;
            int sr2 = 32 + lr + sh - 4;
            int ar2 = ((unsigned)sr2 < 36u) ? sr2 : 36;
            int rb0 = ar0*WP, rs0 = ((ar0 >> 2) & 1) << 3;
            int rb1 = ar1*WP, rs1 = ((ar1 >> 2) & 1) << 3;
            int rb2 = ar2*WP, rs2 = ((ar2 >> 2) & 1) << 3;
            #pragma unroll
            for (int kc = 0; kc < NC; ++kc) {
                int icb = kc*32 + kg*8;
                int d0 = (rb0 + icb) ^ rs0;
                int d1 = (rb1 + icb) ^ rs1;
                int d2 = (rb2 + icb) ^ rs2;
                f16x8 ah[3] = { *(const f16x8*)(shb + d0), *(const f16x8*)(shb + d1),
                                *(const f16x8*)(shb + d2) };
                const short* wbh = cWh + (size_t)(sh*NT*16)*icw + icb;
                f16x8 bh[NT];
                #pragma unroll
                for (int nt = 0; nt < NT; ++nt) bh[nt] = *(const f16x8*)(wbh + (nt*16 + lr)*icw);
                if (SPL) {
                    f16x8 al[3] = { *(const f16x8*)(slb + d0), *(const f16x8*)(slb + d1),
                                    *(const f16x8*)(slb + d2) };
                    const short* wbl = cWl + (size_t)(sh*NT*16)*icw + icb;
                    f16x8 bl[NT];
                    #pragma unroll
                    for (int nt = 0; nt < NT; ++nt) bl[nt] = *(const f16x8*)(wbl + (nt*16 + lr)*icw);
                    #pragma unroll
                    for (int nt = 0; nt < NT; ++nt)
                        #pragma unroll
                        for (int mt = 0; mt < 3; ++mt)
                            acc[mt][nt] = __builtin_amdgcn_mfma_f32_16x16x32_f16(ah[mt], bh[nt], acc[mt][nt], 0,0,0);
                    #pragma unroll
                    for (int nt = 0; nt < NT; ++nt)
                        #pragma unroll
                        for (int mt = 0; mt < 3; ++mt)
                            acc[mt][nt] = __builtin_amdgcn_mfma_f32_16x16x32_f16(ah[mt], bl[nt], acc[mt][nt], 0,0,0);
                    #pragma unroll
                    for (int nt = 0; nt < NT; ++nt)
                        #pragma unroll
                        for (int mt = 0; mt < 3; ++mt)
                            acc[mt][nt] = __builtin_amdgcn_mfma_f32_16x16x32_f16(al[mt], bh[nt], acc[mt][nt], 0,0,0);
                } else {
                    #pragma unroll
                    for (int nt = 0; nt < NT; ++nt)
                        #pragma unroll
                        for (int mt = 0; mt < 3; ++mt)
                            acc[mt][nt] = __builtin_amdgcn_mfma_f32_16x16x32_f16(ah[mt], bh[nt], acc[mt][nt], 0,0,0);
                }
            }
        }
        __syncthreads();
        float* red = (float*)smR;
        if (wv == 2) {
            #pragma unroll
            for (int mt = 0; mt < 3; ++mt)
                #pragma unroll
                for (int nt = 0; nt < NT; ++nt)
                    *(f32x4*)(red + ((size_t)(mt*NT + nt))*256 + lane*4) = acc[mt][nt];
        }
        __syncthreads();
        if (wv == 1) {
            #pragma unroll
            for (int mt = 0; mt < 3; ++mt)
                #pragma unroll
                for (int nt = 0; nt < NT; ++nt) {
                    f32x4* p = (f32x4*)(red + ((size_t)(mt*NT + nt))*256 + lane*4);
                    *p = *p + acc[mt][nt];
                }
        }
        __syncthreads();
        if (wv == 0) {
            constexpr int OC = NT * 16;
            #pragma unroll
            for (int nt = 0; nt < NT; ++nt) {
                int oc = nt*16 + lr;
                float sc = csc[oc], bi = cbi[oc];
                #pragma unroll
                for (int mt = 0; mt < 3; ++mt) {
                    f32x4 a = acc[mt][nt] + *(const f32x4*)(red + ((size_t)(mt*NT + nt))*256 + lane*4);
                    #pragma unroll
                    for (int i = 0; i < 4; ++i) {
                        int s = mt*16 + kg*4 + i;
                        if (s < 36) {
                            float v = fmaxf(a[i]*sc + bi, 0.f);
                            short h, l; splith(v, h, l);
                            outH[(size_t)row*36*OC + s*OC + oc] = h;   // k = s*64+oc
                            outL[(size_t)row*36*OC + s*OC + oc] = l;
                        }
                    }
                }
            }
        }
    }
}

// ---------------- fc(2304->64) fp16-split MFMA (K-split over 4 waves) + LayerNorm + relu ----------------
__global__ __launch_bounds__(256) void k_fc_mfma(
        const short* __restrict__ Ah, const short* __restrict__ Al,
        const short* __restrict__ Bh, const short* __restrict__ Bl,
        const float* __restrict__ fcb,
        const float* __restrict__ gamma, const float* __restrict__ beta,
        float* __restrict__ roi) {
    __shared__ float red[3 * 4 * 256];
    __shared__ float lnb[16][65];
    int tid = threadIdx.x;
    int wv = tid >> 6, lane = tid & 63;
    int lr = lane & 15, kg = lane >> 4;
    int row0 = blockIdx.x * 16;
    f32x4 acc[4] = {};
    for (int kk = 0; kk < 18; ++kk) {
        int k = (wv*18 + kk)*32 + kg*8;
        size_t ar = (size_t)(row0 + lr)*2304 + k;
        f16x8 ah = *(const f16x8*)(Ah + ar);
        f16x8 al = *(const f16x8*)(Al + ar);
        f16x8 bh[4], bl[4];
        #pragma unroll
        for (int nt = 0; nt < 4; ++nt) {
            size_t br = (size_t)(nt*16 + lr)*2304 + k;
            bh[nt] = *(const f16x8*)(Bh + br);
            bl[nt] = *(const f16x8*)(Bl + br);
        }
        #pragma unroll
        for (int nt = 0; nt < 4; ++nt)
            acc[nt] = __builtin_amdgcn_mfma_f32_16x16x32_f16(ah, bh[nt], acc[nt], 0,0,0);
        #pragma unroll
        for (int nt = 0; nt < 4; ++nt)
            acc[nt] = __builtin_amdgcn_mfma_f32_16x16x32_f16(ah, bl[nt], acc[nt], 0,0,0);
        #pragma unroll
        for (int nt = 0; nt < 4; ++nt)
            acc[nt] = __builtin_amdgcn_mfma_f32_16x16x32_f16(al, bh[nt], acc[nt], 0,0,0);
    }
    if (wv > 0) {
        #pragma unroll
        for (int nt = 0; nt < 4; ++nt)
            *(f32x4*)(red + ((size_t)((wv-1)*4 + nt))*256 + lane*4) = acc[nt];
    }
    __syncthreads();
    if (wv == 0) {
        #pragma unroll
        for (int nt = 0; nt < 4; ++nt) {
            f32x4 a = acc[nt]
                    + *(const f32x4*)(red + ((size_t)(0*4 + nt))*256 + lane*4)
                    + *(const f32x4*)(red + ((size_t)(1*4 + nt))*256 + lane*4)
                    + *(const f32x4*)(red + ((size_t)(2*4 + nt))*256 + lane*4);
            #pragma unroll
            for (int i = 0; i < 4; ++i)
                lnb[kg*4 + i][nt*16 + lr] = a[i];
        }
    }
    __syncthreads();
    #pragma unroll
    for (int rr = 0; rr < 4; ++rr) {
        int r = wv*4 + rr;
        float y = lnb[r][lane] + fcb[lane];
        float sum = y;
        #pragma unroll
        for (int off = 32; off > 0; off >>= 1) sum += __shfl_xor(sum, off);
        float mu = sum * (1.f/64.f);
        float d = y - mu;
        float vs = d * d;
        #pragma unroll
        for (int off = 32; off > 0; off >>= 1) vs += __shfl_xor(vs, off);
        float var = vs * (1.f/64.f);
        float outv = d * (1.0f / sqrtf(var + 1e-5f)) * gamma[lane] + beta[lane];
        roi[(size_t)(row0 + r)*64 + lane] = fmaxf(outv, 0.f);
    }
}

// ---------------- key/value maps at the 250 resize-nearest pixels (featT, coalesced) ----------------
__global__ __launch_bounds__(64) void k_keyval(const float* __restrict__ featT, int H, int W,
        const float* __restrict__ kw, const float* __restrict__ ks, const float* __restrict__ kb,
        const float* __restrict__ vw, const float* __restrict__ vb,
        float* __restrict__ keymap, float* __restrict__ valmap) {
    int site = blockIdx.x;
    int b = site / NPIX, n = site % NPIX;
    int r = n / 25, q = n % 25;
    int y = r * H / 10, x = q * W / 25;
    __shared__ float xv[64];
    int tid = threadIdx.x;
    xv[tid] = featT[((size_t)(b * H + y) * W + x) * 64 + tid];
    __syncthreads();
    float ak0 = 0.f, ak1 = 0.f, av0 = 0.f, av1 = 0.f;
    #pragma unroll 4
    for (int c = 0; c < 64; c += 2) {
        float f0 = xv[c], f1 = xv[c+1];
        ak0 += f0 * kw[tid*64 + c];
        ak1 += f1 * kw[tid*64 + c + 1];
        av0 += f0 * vw[tid*64 + c];
        av1 += f1 * vw[tid*64 + c + 1];
    }
    float ak = ak0 + ak1, av = av0 + av1;
    keymap[(size_t)(b*64 + tid) * NPIX + n] = fmaxf(ak * ks[tid] + kb[tid], 0.f);
    valmap[(size_t)(b*NPIX + n) * 64 + tid] = av + vb[tid];
}

// ---------------- attention (250 keys), roi updated in place ----------------
__global__ __launch_bounds__(256) void k_attn(float* __restrict__ roi,
        const float* __restrict__ keymap, const float* __restrict__ valmap,
        const float* __restrict__ fqw, const float* __restrict__ fqb,
        const float* __restrict__ aws, const float* __restrict__ awb) {
    int rI = blockIdx.x;
    int b = rI / PPRI, p = rI % PPRI;
    __shared__ float q[64];
    __shared__ float sc[256];
    __shared__ float red[4];
    __shared__ float pv[4][64];
    int tid = threadIdx.x;
    if (tid < 64) q[tid] = fmaxf(roi[(size_t)rI*64 + tid] * fqw[p] + fqb[p], 0.f);
    __syncthreads();
    float s = -INFINITY;
    if (tid < NPIX) {
        const float* km = keymap + (size_t)b*64*NPIX + tid;
        float a0 = 0.f, a1 = 0.f, a2 = 0.f, a3 = 0.f;
        #pragma unroll 4
        for (int c = 0; c < 64; c += 4) {
            a0 += q[c  ] * km[(c  )*NPIX];
            a1 += q[c+1] * km[(c+1)*NPIX];
            a2 += q[c+2] * km[(c+2)*NPIX];
            a3 += q[c+3] * km[(c+3)*NPIX];
        }
        s = ((a0 + a1) + (a2 + a3)) * 0.125f;
    }
    float m = s;
    #pragma unroll
    for (int off = 32; off > 0; off >>= 1) m = fmaxf(m, __shfl_xor(m, off));
    if ((tid & 63) == 0) red[tid >> 6] = m;
    __syncthreads();
    m = fmaxf(fmaxf(red[0], red[1]), fmaxf(red[2], red[3]));
    __syncthreads();
    float e = (tid < NPIX) ? expf(s - m) : 0.f;
    sc[tid] = e;
    float su = e;
    #pragma unroll
    for (int off = 32; off > 0; off >>= 1) su += __shfl_xor(su, off);
    if ((tid & 63) == 0) red[tid >> 6] = su;
    __syncthreads();
    su = red[0] + red[1] + red[2] + red[3];
    float inv = 1.f / su;
    int w = tid >> 6, c = tid & 63;
    int n0 = w * 64, n1 = min(NPIX, n0 + 64);
    const float* vm = valmap + (size_t)b*NPIX*64 + c;
    float b0 = 0.f, b1 = 0.f, b2 = 0.f, b3 = 0.f;
    int n = n0;
    for (; n + 3 < n1; n += 4) {
        b0 += sc[n  ] * vm[(size_t)(n  )*64];
        b1 += sc[n+1] * vm[(size_t)(n+1)*64];
        b2 += sc[n+2] * vm[(size_t)(n+2)*64];
        b3 += sc[n+3] * vm[(size_t)(n+3)*64];
    }
    for (; n < n1; ++n) b0 += sc[n] * vm[(size_t)n*64];
    pv[w][c] = (b0 + b1) + (b2 + b3);
    __syncthreads();
    if (tid < 64) {
        float acc = (pv[0][tid] + pv[1][tid]) + (pv[2][tid] + pv[3][tid]);
        size_t o = (size_t)rI*64 + tid;
        roi[o] = roi[o] + (acc * inv) * aws[p] + awb[p];
    }
}

// coalesced matvec, 4-acc ILP: out[tid] = sum_c v[c] * WT[c*ld + tid]
__device__ inline float dotT(const float* __restrict__ v, const float* __restrict__ wT, int ld) {
    float a0 = 0.f, a1 = 0.f, a2 = 0.f, a3 = 0.f;
    #pragma unroll 4
    for (int c = 0; c < 64; c += 4) {
        a0 += v[c  ] * wT[(c  )*ld];
        a1 += v[c+1] * wT[(c+1)*ld];
        a2 += v[c+2] * wT[(c+2)*ld];
        a3 += v[c+3] * wT[(c+3)*ld];
    }
    return (a0 + a1) + (a2 + a3);
}

// ---------------- heads: reg (+ cls at stage 2), geometry, prior update / output ----------------
__global__ __launch_bounds__(128) void k_head(int stage,
        float* __restrict__ p234g, float* __restrict__ pofm,
        const float* __restrict__ roi,
        const float* __restrict__ rw1T, const float* __restrict__ rb1,
        const float* __restrict__ rw2T, const float* __restrict__ rb2,
        const float* __restrict__ rhwT, const float* __restrict__ rhb,
        const float* __restrict__ cw1T, const float* __restrict__ cb1,
        const float* __restrict__ cw2T, const float* __restrict__ cb2,
        const float* __restrict__ chwT, const float* __restrict__ chb,
        float* __restrict__ out) {
    int rI = blockIdx.x;
    int b = rI / PPRI, p = rI % PPRI;
    int src = p * NB + b;                     // ff row scramble
    __shared__ float ff[64], h1[64], h2[64], rg[76];
    int tid = threadIdx.x;
    if (tid < 64) ff[tid] = roi[(size_t)src*64 + tid];
    __syncthreads();
    if (tid < 64) h1[tid] = fmaxf(dotT(ff, rw1T + tid, 64) + rb1[tid], 0.f);
    __syncthreads();
    if (tid < 64) h2[tid] = fmaxf(dotT(h1, rw2T + tid, 64) + rb2[tid], 0.f);
    __syncthreads();
    if (tid < 76) rg[tid] = dotT(h2, rhwT + tid, 76) + rhb[tid];
    __syncthreads();
    float* p234 = p234g + (size_t)rI * 3;
    float p2 = p234[0] + rg[0];
    float p3 = p234[1] + rg[1];
    float p4 = p234[2] + rg[2];
    float tanv = tanf(p4 * FPI + 1e-5f);
    if (stage < 2) {
        if (tid == 0) { p234[0] = p2; p234[1] = p3; p234[2] = p4; }
        if (tid < 36) {
            int k = (tid == 35) ? 71 : 2*tid;
            float prior_y = (float)(1.0 - (double)k / 71.0);
            float geom = (p3 * 799.0f + ((1.0f - prior_y - p2) * 320.0f) / tanv) / 799.0f;
            pofm[(size_t)rI * 36 + tid] = geom;
        }
    } else {
        if (tid < 64) h1[tid] = fmaxf(dotT(ff, cw1T + tid, 64) + cb1[tid], 0.f);
        __syncthreads();
        if (tid < 64) h2[tid] = fmaxf(dotT(h1, cw2T + tid, 64) + cb2[tid], 0.f);
        __syncthreads();
        float* ob = out + (size_t)rI * 78;
        if (tid < 2) ob[tid] = dotT(h2, chwT + tid, 2) + chb[tid];
        if (tid == 64) { ob[2] = p2; ob[3] = p3; ob[4] = p4; ob[5] = rg[3]; }
        if (tid < 72) {
            int k = tid;
            float prior_y = (float)(1.0 - (double)k / 71.0);
            float geom = (p3 * 799.0f + ((1.0f - prior_y - p2) * 320.0f) / tanv) / 799.0f;
            ob[6 + k] = geom + rg[4 + k];
        }
    }
}

// ---------------- final category + attribute heads ----------------
__global__ __launch_bounds__(64) void k_catattr(const float* __restrict__ roi,
        const float* __restrict__ cw1T, const float* __restrict__ cb1,
        const float* __restrict__ cw2T, const float* __restrict__ cb2,
        const float* __restrict__ protoNT,
        const float* __restrict__ aw1T, const float* __restrict__ ab1,
        const float* __restrict__ aw2T, const float* __restrict__ ab2,
        const float* __restrict__ ahwT, const float* __restrict__ ahb,
        float* __restrict__ out) {
    const size_t CAT_OFF = (size_t)BP * 78;
    const size_t ATTR_OFF = CAT_OFF + (size_t)BP * 15;
    int rI = blockIdx.x;
    int b = rI / PPRI, p = rI % PPRI;
    int src = p * NB + b;
    __shared__ float ff[64], h1[64], h2[64];
    int tid = threadIdx.x;
    ff[tid] = roi[(size_t)src*64 + tid];
    __syncthreads();
    h1[tid] = fmaxf(dotT(ff, cw1T + tid, 64) + cb1[tid], 0.f);
    __syncthreads();
    float v = fmaxf(dotT(h1, cw2T + tid, 64) + cb2[tid], 0.f);
    float ssq = v * v;
    #pragma unroll
    for (int off = 32; off > 0; off >>= 1) ssq += __shfl_xor(ssq, off);
    float nrm = fmaxf(sqrtf(ssq), 1e-12f);
    h2[tid] = v / nrm;
    __syncthreads();
    if (tid < 15) out[CAT_OFF + (size_t)rI*15 + tid] = dotT(h2, protoNT + tid, 15) * 20.0f;
    __syncthreads();
    h1[tid] = fmaxf(dotT(ff, aw1T + tid, 64) + ab1[tid], 0.f);
    __syncthreads();
    float va = fmaxf(dotT(h1, aw2T + tid, 64) + ab2[tid], 0.f);
    h2[tid] = va;
    __syncthreads();
    if (tid < 4) out[ATTR_OFF + (size_t)rI*4 + tid] = dotT(h2, ahwT + tid, 4) + ahb[tid];
}

extern "C" void kernel_launch(void* const* d_in, const int* in_sizes, int n_in,
                              void* d_out, int out_size, void* d_ws, size_t ws_size,
                              hipStream_t stream) {
    (void)in_sizes; (void)n_in; (void)out_size; (void)ws_size;
    const float* feat_s8   = (const float*)d_in[0];
    const float* feat_s16  = (const float*)d_in[1];
    const float* feat_s32  = (const float*)d_in[2];
    const float* rg_conv_w     = (const float*)d_in[3];
    const float* rg_conv_scale = (const float*)d_in[4];
    const float* rg_conv_bias  = (const float*)d_in[5];
    const float* catconv_w[3]  = {(const float*)d_in[6], (const float*)d_in[7], (const float*)d_in[8]};
    const float* catconv_scale = (const float*)d_in[9];
    const float* catconv_bias  = (const float*)d_in[10];
    const float* fc_w = (const float*)d_in[11];
    const float* fc_b = (const float*)d_in[12];
    const float* ln_gamma = (const float*)d_in[13];
    const float* ln_beta  = (const float*)d_in[14];
    const float* fkey_w = (const float*)d_in[15];
    const float* fkey_scale = (const float*)d_in[16];
    const float* fkey_bias  = (const float*)d_in[17];
    const float* fvalue_w = (const float*)d_in[18];
    const float* fvalue_b = (const float*)d_in[19];
    const float* fquery_w = (const float*)d_in[20];
    const float* fquery_b = (const float*)d_in[21];
    const float* attn_w_scale = (const float*)d_in[22];
    const float* attn_w_bias  = (const float*)d_in[23];
    const float* cls_w1 = (const float*)d_in[24];
    const float* cls_b1 = (const float*)d_in[25];
    const float* cls_w2 = (const float*)d_in[26];
    const float* cls_b2 = (const float*)d_in[27];
    const float* reg_w1 = (const float*)d_in[28];
    const float* reg_b1 = (const float*)d_in[29];
    const float* reg_w2 = (const float*)d_in[30];
    const float* reg_b2 = (const float*)d_in[31];
    const float* cls_head_w = (const float*)d_in[32];
    const float* cls_head_b = (const float*)d_in[33];
    const float* reg_head_w = (const float*)d_in[34];
    const float* reg_head_b = (const float*)d_in[35];
    const float* cat_w1 = (const float*)d_in[36];
    const float* cat_b1 = (const float*)d_in[37];
    const float* cat_w2 = (const float*)d_in[38];
    const float* cat_b2 = (const float*)d_in[39];
    const float* prototypes = (const float*)d_in[40];
    const float* attr_w1 = (const float*)d_in[41];
    const float* attr_b1 = (const float*)d_in[42];
    const float* attr_w2 = (const float*)d_in[43];
    const float* attr_b2 = (const float*)d_in[44];
    const float* attr_head_w = (const float*)d_in[45];
    const float* attr_head_b = (const float*)d_in[46];

    float* ws = (float*)d_ws;
    // fp32 region (float offsets, all 16B-aligned)
    float* pofm   = ws;                        // 221,184
    float* p234   = ws + 221184;               // 18,432
    short* fcBh   = (short*)(ws + 240576);     // 147,456 sh
    short* fcBl   = (short*)(ws + 314304);     // 147,456 sh
    float* roi    = ws + 388032;               // 393,216
    float* keymap = ws + 781248;               // 512,000
    float* valmap = ws + 1293248;              // 512,000
    short* catHh  = (short*)(ws + 1805248);    // 14,155,776 sh
    short* catHl  = (short*)(ws + 8883136);    // 14,155,776 sh
    float* featT  = ws + 15961024;             // 8,192,000 fp32 (max 32*4000*64)
    // fp16 buffers (short*, offsets in floats)
    short* rgCh   = (short*)(ws + 30116800);   // 31,850,496 sh (3 stages)
    short* rgCl   = (short*)(ws + 46042048);   // 31,850,496 sh
    short* rgWh   = (short*)(ws + 61967296);   // 82,944 sh
    short* rgWl   = (short*)(ws + 62008768);   // 82,944 sh
    short* catWh  = (short*)(ws + 62050240);   // 184,320 sh
    short* catWl  = (short*)(ws + 62142400);   // 184,320 sh
    // transposed head weights (fp32)
    float* hT      = ws + 62234560;            // 32,768 (8 x 64x64, [c][o])
    float* rhwT    = ws + 62267328;            // 4,864
    float* chwT    = ws + 62272192;            // 128
    float* ahwT    = ws + 62272320;            // 256
    float* protoNT = ws + 62272576;            // 960

    float* out = (float*)d_out;

    k_init<<<864, 256, 0, stream>>>(pofm, p234, fcBh, fcBl, fc_w, prototypes,
                                    rgWh, rgWl, rg_conv_w, catWh, catWl,
                                    catconv_w[0], catconv_w[1], catconv_w[2],
                                    hT, rhwT, chwT, ahwT, protoNT,
                                    reg_w1, reg_w2, cls_w1, cls_w2,
                                    cat_w1, cat_w2, attr_w1, attr_w2,
                                    reg_head_w, cls_head_w, attr_head_w);

    const float* feats[3] = {feat_s32, feat_s16, feat_s8};
    const int Hs[3] = {10, 20, 40}, Wstg[3] = {25, 50, 100};
    const int catbase[3] = {0, 36864, 92160};

    for (int st = 0; st < 3; ++st) {
        int HW = Hs[st] * Wstg[st];
        k_transpose<<<dim3((HW + 63)/64, NB), 256, 0, stream>>>(feats[st], featT, HW);
        // fused gridsample + rg conv + cat conv
        if (st == 0)
            k_rgcat<2,4,48,80,48,0,true,true><<<BP, 192, 0, stream>>>(
                    featT, Hs[0], Wstg[0], pofm,
                    rgWh, rgWl, rg_conv_scale, rg_conv_bias,
                    catWh + catbase[0], catWl + catbase[0], catconv_scale, catconv_bias,
                    rgCh, rgCl, rgCh, rgCl, catHh, catHl);
        else if (st == 1)
            k_rgcat<3,4,48,112,96,48,true,true><<<BP, 192, 0, stream>>>(
                    featT, Hs[1], Wstg[1], pofm,
                    rgWh + 27648, rgWl + 27648, rg_conv_scale + 48, rg_conv_bias + 48,
                    catWh + catbase[1], catWl + catbase[1], catconv_scale + 64, catconv_bias + 64,
                    rgCh + (size_t)BP*1728, rgCl + (size_t)BP*1728, rgCh, rgCl, catHh, catHl);
        else
            k_rgcat<5,4,48,176,144,96,false,false><<<BP, 192, 0, stream>>>(
                    featT, Hs[2], Wstg[2], pofm,
                    rgWh + 2*27648, rgWl + 2*27648, rg_conv_scale + 96, rg_conv_bias + 96,
                    catWh + catbase[2], catWl + catbase[2], catconv_scale + 128, catconv_bias + 128,
                    nullptr, nullptr, rgCh, rgCl, catHh, catHl);
        k_fc_mfma<<<384, 256, 0, stream>>>(catHh, catHl, fcBh, fcBl,
                                           fc_b, ln_gamma, ln_beta, roi);
        k_keyval<<<NB*NPIX, 64, 0, stream>>>(featT, Hs[st], Wstg[st],
                                             fkey_w, fkey_scale, fkey_bias,
                                             fvalue_w, fvalue_b, keymap, valmap);
        k_attn<<<BP, 256, 0, stream>>>(roi, keymap, valmap, fquery_w, fquery_b,
                                       attn_w_scale, attn_w_bias);
        k_head<<<BP, 128, 0, stream>>>(st, p234, pofm, roi,
                                       hT + 0, reg_b1, hT + 4096, reg_b2, rhwT, reg_head_b,
                                       hT + 8192, cls_b1, hT + 12288, cls_b2, chwT, cls_head_b,
                                       out);
    }
    k_catattr<<<BP, 64, 0, stream>>>(roi, hT + 16384, cat_b1, hT + 20480, cat_b2, protoNT,
                                     hT + 24576, attr_b1, hT + 28672, attr_b2,
                                     ahwT, attr_head_b, out);
}

// Round 17
// 1034.367 us; speedup vs baseline: 1.0847x; 1.0847x over previous
//
#include <hip/hip_runtime.h>
#include <math.h>

#define PPRI 192
#define NB   32
#define NS   36
#define BP   6144   // NB*PPRI
#define NPIX 250
#define FPI  3.14159265358979323846f

typedef _Float16 f16x8 __attribute__((ext_vector_type(8)));
typedef float f32x4  __attribute__((ext_vector_type(4)));

__device__ inline short f2h(float x) {
    _Float16 h = (_Float16)x;
    return *(short*)&h;
}
__device__ inline float h2f(short s) {
    _Float16 h = *(_Float16*)&s;
    return (float)h;
}
__device__ inline void splith(float x, short& h, short& l) {
    h = f2h(x); l = f2h(x - h2f(h));
}

// ---------------- init: pofm, p234, fc weights fp16 hi/lo, conv weights fp16 hi/lo,
//                   transposed head weights (coalesced [c][o] layouts) ----------------
__global__ void k_init(float* __restrict__ pofm, float* __restrict__ p234,
                       short* __restrict__ fcBh, short* __restrict__ fcBl,
                       const float* __restrict__ fc_w, const float* __restrict__ protos,
                       short* __restrict__ rgWh, short* __restrict__ rgWl,
                       const float* __restrict__ rg_w,
                       short* __restrict__ catWh, short* __restrict__ catWl,
                       const float* __restrict__ cw0, const float* __restrict__ cw1,
                       const float* __restrict__ cw2,
                       float* __restrict__ hT, float* __restrict__ rhwT,
                       float* __restrict__ chwT, float* __restrict__ ahwT,
                       float* __restrict__ protoNT,
                       const float* __restrict__ reg_w1, const float* __restrict__ reg_w2,
                       const float* __restrict__ cls_w1, const float* __restrict__ cls_w2,
                       const float* __restrict__ cat_w1, const float* __restrict__ cat_w2,
                       const float* __restrict__ attr_w1, const float* __restrict__ attr_w2,
                       const float* __restrict__ reg_head_w, const float* __restrict__ cls_head_w,
                       const float* __restrict__ attr_head_w) {
    int i = blockIdx.x * 256 + threadIdx.x;
    if (i < BP * NS) {
        int p = (i / NS) % PPRI;
        pofm[i] = ((float)p + 0.5f) / 192.0f;
    }
    if (i < BP) {
        p234[3*i+0] = 0.5f; p234[3*i+1] = 0.1f; p234[3*i+2] = 0.0f;
    }
    if (i < 64 * 2304) {           // fcB[o][k], k = s*64+oc  <- fc_w[o][oc*36+s]
        int o = i / 2304, k = i % 2304;
        int s = k >> 6, oc = k & 63;
        short h, l; splith(fc_w[o * 2304 + oc * 36 + s], h, l);
        fcBh[i] = h; fcBl[i] = l;
    }
    if (i < 82944) {               // rgW[st][k][oc][ic] <- rg_w[st][oc][ic][k]
        int st = i / 27648, r = i % 27648;
        int k = r / 3072, r2 = r % 3072;
        int oc = r2 / 64, ic = r2 & 63;
        short h, l; splith(rg_w[((st*48 + oc)*64 + ic)*9 + k], h, l);
        rgWh[i] = h; rgWl[i] = l;
    }
    if (i < 184320) {              // catW[st][k][oc][icp], icw = {64,96,160}
        int st, base, icw; const float* w;
        if (i < 36864)      { st = 0; base = 0;     icw = 64;  w = cw0; }
        else if (i < 92160) { st = 1; base = 36864; icw = 96;  w = cw1; }
        else                { st = 2; base = 92160; icw = 160; w = cw2; }
        int r = i - base;
        int k = r / (64*icw), r2 = r % (64*icw);
        int oc = r2 / icw, icp = r2 % icw;
        int IC = 48 * (st + 1);
        float wv = (icp < IC) ? w[(oc*IC + icp)*9 + k] : 0.f;
        short h, l; splith(wv, h, l);
        catWh[i] = h; catWl[i] = l;
    }
    if (i < 32768) {               // 8 transposed 64x64 head matrices: hT[m][c][o] = W[o][c]
        int m = i >> 12, r2 = i & 4095, c = r2 >> 6, o = r2 & 63;
        const float* Ws[8] = {reg_w1, reg_w2, cls_w1, cls_w2, cat_w1, cat_w2, attr_w1, attr_w2};
        hT[i] = Ws[m][o*64 + c];
    }
    if (i < 76*64) {               // rhwT[c][o] = reg_head_w[o][c]
        int c = i / 76, o = i % 76;
        rhwT[c*76 + o] = reg_head_w[o*64 + c];
    }
    if (i < 128) {                 // chwT[c][o] = cls_head_w[o][c]
        int c = i >> 1, o = i & 1;
        chwT[c*2 + o] = cls_head_w[o*64 + c];
    }
    if (i < 256) {                 // ahwT[c][o] = attr_head_w[o][c]
        int c = i >> 2, o = i & 3;
        ahwT[c*4 + o] = attr_head_w[o*64 + c];
    }
    if (i < 960) {                 // protoNT[c][p] = protos[p][c]/||protos[p]||
        int c = i / 15, p = i % 15;
        float ss = 0.f;
        for (int j = 0; j < 64; ++j) { float v = protos[p*64 + j]; ss += v*v; }
        float nrm = fmaxf(sqrtf(ss), 1e-12f);
        protoNT[c*15 + p] = protos[p*64 + c] / nrm;
    }
}

// ---------------- feat transpose: [b][c][hw] -> featT[b][hw][c] (fp32, exact) ----------------
__global__ __launch_bounds__(256) void k_transpose(const float* __restrict__ in,
                                                   float* __restrict__ outT, int HW) {
    __shared__ float t[64][65];
    int b = blockIdx.y;
    int hw0 = blockIdx.x * 64;
    int tx = threadIdx.x & 63, ty = threadIdx.x >> 6;
    const float* ib = in + (size_t)b * 64 * HW;
    for (int c = ty; c < 64; c += 4) {
        int hw = hw0 + tx;
        t[c][tx] = (hw < HW) ? ib[(size_t)c * HW + hw] : 0.f;
    }
    __syncthreads();
    float* ob = outT + (size_t)b * HW * 64;
    for (int r = ty; r < 64; r += 4) {
        int hw = hw0 + r;
        if (hw < HW) ob[(size_t)hw * 64 + tx] = t[tx][r];
    }
}

// ---------------- fused gridsample + rg conv1d (64->48, k=9, pad=4), split-K over 3 waves ----------------
// SPL=true: fp16 hi/lo 3-MFMA term-major (stages 0/1). SPL=false: fp16 single (stage 2).
#define RGWP 80
template<bool SPL>
__global__ __launch_bounds__(192) void k_rgfused(
        const float* __restrict__ featT, int H, int W,
        const float* __restrict__ pofm,
        const short* __restrict__ Wh, const short* __restrict__ Wl,
        const float* __restrict__ scale, const float* __restrict__ bias,
        short* __restrict__ outH, short* __restrict__ outL) {
    constexpr int STG = (SPL ? 2 : 1) * 37 * RGWP;  // shorts
    constexpr int RED = 9 * 256 * 2;                // 9 tiles x 256 floats, in shorts
    constexpr int SMS = (STG > RED) ? STG : RED;
    __shared__ short sm[SMS];
    int tid = threadIdx.x;
    int row = blockIdx.x;
    int wv = tid >> 6, lane = tid & 63;
    int b = row / PPRI;
    // ---- phase 0: bilinear sample (lane = channel, coalesced corner reads) ----
    float myPof = (lane < 36) ? pofm[row * 36 + lane] : 0.f;
    const float* fb = featT + (size_t)b * H * W * 64;
    for (int si = 0; si < 12; ++si) {
        int s = wv * 12 + si;
        float px = __shfl(myPof, 35 - s);
        px = fminf(fmaxf(px, -1e6f), 1e6f);
        float pfy = (s == 0) ? 0.0f : ((float)(2*s+1) / 71.0f);
        float ix = px  * (float)(W - 1);
        float iy = pfy * (float)(H - 1);
        float x0f = floorf(ix), y0f = floorf(iy);
        float fx = ix - x0f, fy = iy - y0f;
        float vx0 = (x0f >= 0.f     && x0f     <= (float)(W-1)) ? 1.f : 0.f;
        float vx1 = (x0f+1.f >= 0.f && x0f+1.f <= (float)(W-1)) ? 1.f : 0.f;
        float vy0 = (y0f >= 0.f     && y0f     <= (float)(H-1)) ? 1.f : 0.f;
        float vy1 = (y0f+1.f >= 0.f && y0f+1.f <= (float)(H-1)) ? 1.f : 0.f;
        int x0 = min(max((int)x0f, 0), W-1);
        int x1 = min(max((int)x0f + 1, 0), W-1);
        int y0 = min(max((int)y0f, 0), H-1);
        int y1 = min(max((int)y0f + 1, 0), H-1);
        float w00 = (1.f-fx)*(1.f-fy)*vx0*vy0, w10 = fx*(1.f-fy)*vx1*vy0;
        float w01 = (1.f-fx)*fy*vx0*vy1,       w11 = fx*fy*vx1*vy1;
        float v = w00 * fb[(size_t)(y0*W+x0)*64 + lane]
                + w10 * fb[(size_t)(y0*W+x1)*64 + lane]
                + w01 * fb[(size_t)(y1*W+x0)*64 + lane]
                + w11 * fb[(size_t)(y1*W+x1)*64 + lane];
        int di = (s*RGWP + lane) ^ (((s >> 2) & 1) << 3);
        if (SPL) {
            short h, l; splith(v, h, l);
            sm[di] = h;
            sm[37*RGWP + di] = l;
        } else {
            sm[di] = f2h(v);
        }
    }
    if (wv == 0) {                 // zero sentinel row 36
        int di = (36*RGWP + lane) ^ 8;
        sm[di] = 0;
        if (SPL) sm[37*RGWP + di] = 0;
    }
    __syncthreads();
    // ---- rgconv split-K compute (NC=2, NT=3), term-major MFMA groups ----
    int lr = lane & 15, kg = lane >> 4;
    const short* shb = sm;
    const short* slb = sm + 37*RGWP;
    f32x4 acc[3][3] = {};
    #pragma unroll
    for (int ssh = 0; ssh < 3; ++ssh) {
        int sh = wv*3 + ssh;
        int sr0 = lr + sh - 4;
        int ar0 = ((unsigned)sr0 < 36u) ? sr0 : 36;
        int ar1 = 16 + lr + sh - 4;
        int sr2 = 32 + lr + sh - 4;
        int ar2 = ((unsigned)sr2 < 36u) ? sr2 : 36;
        int rb0 = ar0*RGWP, rs0 = ((ar0 >> 2) & 1) << 3;
        int rb1 = ar1*RGWP, rs1 = ((ar1 >> 2) & 1) << 3;
        int rb2 = ar2*RGWP, rs2 = ((ar2 >> 2) & 1) << 3;
        #pragma unroll
        for (int kc = 0; kc < 2; ++kc) {
            int icb = kc*32 + kg*8;
            int d0 = (rb0 + icb) ^ rs0;
            int d1 = (rb1 + icb) ^ rs1;
            int d2 = (rb2 + icb) ^ rs2;
            f16x8 ah[3] = { *(const f16x8*)(shb + d0), *(const f16x8*)(shb + d1),
                            *(const f16x8*)(shb + d2) };
            const short* wbh = Wh + (size_t)(sh*48)*64 + icb;
            f16x8 bh[3];
            #pragma unroll
            for (int nt = 0; nt < 3; ++nt) bh[nt] = *(const f16x8*)(wbh + (nt*16 + lr)*64);
            if (SPL) {
                f16x8 al[3] = { *(const f16x8*)(slb + d0), *(const f16x8*)(slb + d1),
                                *(const f16x8*)(slb + d2) };
                const short* wbl = Wl + (size_t)(sh*48)*64 + icb;
                f16x8 bl[3];
                #pragma unroll
                for (int nt = 0; nt < 3; ++nt) bl[nt] = *(const f16x8*)(wbl + (nt*16 + lr)*64);
                // term-major: three groups of 9 independent MFMAs; per-tile order hh->hl->lh preserved
                #pragma unroll
                for (int nt = 0; nt < 3; ++nt)
                    #pragma unroll
                    for (int mt = 0; mt < 3; ++mt)
                        acc[mt][nt] = __builtin_amdgcn_mfma_f32_16x16x32_f16(ah[mt], bh[nt], acc[mt][nt], 0,0,0);
                #pragma unroll
                for (int nt = 0; nt < 3; ++nt)
                    #pragma unroll
                    for (int mt = 0; mt < 3; ++mt)
                        acc[mt][nt] = __builtin_amdgcn_mfma_f32_16x16x32_f16(ah[mt], bl[nt], acc[mt][nt], 0,0,0);
                #pragma unroll
                for (int nt = 0; nt < 3; ++nt)
                    #pragma unroll
                    for (int mt = 0; mt < 3; ++mt)
                        acc[mt][nt] = __builtin_amdgcn_mfma_f32_16x16x32_f16(al[mt], bh[nt], acc[mt][nt], 0,0,0);
            } else {
                #pragma unroll
                for (int nt = 0; nt < 3; ++nt)
                    #pragma unroll
                    for (int mt = 0; mt < 3; ++mt)
                        acc[mt][nt] = __builtin_amdgcn_mfma_f32_16x16x32_f16(ah[mt], bh[nt], acc[mt][nt], 0,0,0);
            }
        }
    }
    __syncthreads();
    float* red = (float*)sm;
    if (wv == 2) {
        #pragma unroll
        for (int mt = 0; mt < 3; ++mt)
            #pragma unroll
            for (int nt = 0; nt < 3; ++nt)
                *(f32x4*)(red + ((size_t)(mt*3 + nt))*256 + lane*4) = acc[mt][nt];
    }
    __syncthreads();
    if (wv == 1) {
        #pragma unroll
        for (int mt = 0; mt < 3; ++mt)
            #pragma unroll
            for (int nt = 0; nt < 3; ++nt) {
                f32x4* p = (f32x4*)(red + ((size_t)(mt*3 + nt))*256 + lane*4);
                *p = *p + acc[mt][nt];
            }
    }
    __syncthreads();
    if (wv == 0) {
        #pragma unroll
        for (int nt = 0; nt < 3; ++nt) {
            int oc = nt*16 + lr;
            float sc = scale[oc], bi = bias[oc];
            #pragma unroll
            for (int mt = 0; mt < 3; ++mt) {
                f32x4 a = acc[mt][nt] + *(const f32x4*)(red + ((size_t)(mt*3 + nt))*256 + lane*4);
                #pragma unroll
                for (int i = 0; i < 4; ++i) {
                    int s = mt*16 + kg*4 + i;
                    if (s < 36) {
                        float v = fmaxf(a[i]*sc + bi, 0.f);
                        if (SPL) {
                            short h, l; splith(v, h, l);
                            outH[(size_t)row*36*48 + s*48 + oc] = h;
                            outL[(size_t)row*36*48 + s*48 + oc] = l;
                        } else {
                            outH[(size_t)row*36*48 + s*48 + oc] = f2h(v);
                        }
                    }
                }
            }
        }
    }
}

// ---------------- cat conv1d (k=9, pad=4), split-K over 3 waves; term-major MFMA; fp16 hi/lo out ----------------
template<int NC, int NT, int BW, int WP, int ICR, bool SPL>
__global__ __launch_bounds__(192) void k_catconv(
        const short* __restrict__ Xh, const short* __restrict__ Xl,
        const short* __restrict__ Wh, const short* __restrict__ Wl,
        const float* __restrict__ scale, const float* __restrict__ bias,
        short* __restrict__ outH, short* __restrict__ outL) {
    constexpr int icw = NC * 32;
    constexpr int CH  = icw / 8;
    constexpr int STG = (SPL ? 2 : 1) * 37 * WP;
    constexpr int RED = 3 * NT * 256 * 2;
    constexpr int SMS = (STG > RED) ? STG : RED;
    __shared__ short sm[SMS];
    int tid = threadIdx.x;
    int row = blockIdx.x;
    for (int idx = tid; idx < 37*CH; idx += 192) {
        int pos = idx / CH, c0 = (idx % CH) << 3;
        f16x8 h = {}, l = {};
        if (pos < 36 && c0 < ICR) {
            int sidx = c0 / BW, cc = c0 % BW;
            size_t src = ((size_t)(sidx*BP + row)*36 + pos)*BW + cc;
            h = *(const f16x8*)(Xh + src);
            if (SPL) l = *(const f16x8*)(Xl + src);
        }
        int di = (pos*WP + c0) ^ (((pos >> 2) & 1) << 3);
        *(f16x8*)(sm + di) = h;
        if (SPL) *(f16x8*)(sm + 37*WP + di) = l;
    }
    __syncthreads();
    int wv = tid >> 6, lane = tid & 63;
    int lr = lane & 15, kg = lane >> 4;
    const short* shb = sm;
    const short* slb = sm + 37*WP;
    f32x4 acc[3][NT] = {};
    #pragma unroll
    for (int ssh = 0; ssh < 3; ++ssh) {
        int sh = wv*3 + ssh;
        int sr0 = lr + sh - 4;
        int ar0 = ((unsigned)sr0 < 36u) ? sr0 : 36;
        int ar1 = 16 + lr + sh - 4;
        int sr2 = 32 + lr + sh - 4;
        int ar2 = ((unsigned)sr2 < 36u) ? sr2 : 36;
        int rb0 = ar0*WP, rs0 = ((ar0 >> 2) & 1) << 3;
        int rb1 = ar1*WP, rs1 = ((ar1 >> 2) & 1) << 3;
        int rb2 = ar2*WP, rs2 = ((ar2 >> 2) & 1) << 3;
        #pragma unroll
        for (int kc = 0; kc < NC; ++kc) {
            int icb = kc*32 + kg*8;
            int d0 = (rb0 + icb) ^ rs0;
            int d1 = (rb1 + icb) ^ rs1;
            int d2 = (rb2 + icb) ^ rs2;
            f16x8 ah[3] = { *(const f16x8*)(shb + d0), *(const f16x8*)(shb + d1),
                            *(const f16x8*)(shb + d2) };
            const short* wbh = Wh + (size_t)(sh*NT*16)*icw + icb;
            f16x8 bh[NT];
            #pragma unroll
            for (int nt = 0; nt < NT; ++nt) bh[nt] = *(const f16x8*)(wbh + (nt*16 + lr)*icw);
            if (SPL) {
                f16x8 al[3] = { *(const f16x8*)(slb + d0), *(const f16x8*)(slb + d1),
                                *(const f16x8*)(slb + d2) };
                const short* wbl = Wl + (size_t)(sh*NT*16)*icw + icb;
                f16x8 bl[NT];
                #pragma unroll
                for (int nt = 0; nt < NT; ++nt) bl[nt] = *(const f16x8*)(wbl + (nt*16 + lr)*icw);
                // term-major: three groups of 3*NT independent MFMAs; per-tile order hh->hl->lh preserved
                #pragma unroll
                for (int nt = 0; nt < NT; ++nt)
                    #pragma unroll
                    for (int mt = 0; mt < 3; ++mt)
                        acc[mt][nt] = __builtin_amdgcn_mfma_f32_16x16x32_f16(ah[mt], bh[nt], acc[mt][nt], 0,0,0);
                #pragma unroll
                for (int nt = 0; nt < NT; ++nt)
                    #pragma unroll
                    for (int mt = 0; mt < 3; ++mt)
                        acc[mt][nt] = __builtin_amdgcn_mfma_f32_16x16x32_f16(ah[mt], bl[nt], acc[mt][nt], 0,0,0);
                #pragma unroll
                for (int nt = 0; nt < NT; ++nt)
                    #pragma unroll
                    for (int mt = 0; mt < 3; ++mt)
                        acc[mt][nt] = __builtin_amdgcn_mfma_f32_16x16x32_f16(al[mt], bh[nt], acc[mt][nt], 0,0,0);
            } else {
                #pragma unroll
                for (int nt = 0; nt < NT; ++nt)
                    #pragma unroll
                    for (int mt = 0; mt < 3; ++mt)
                        acc[mt][nt] = __builtin_amdgcn_mfma_f32_16x16x32_f16(ah[mt], bh[nt], acc[mt][nt], 0,0,0);
            }
        }
    }
    __syncthreads();
    float* red = (float*)sm;
    if (wv == 2) {
        #pragma unroll
        for (int mt = 0; mt < 3; ++mt)
            #pragma unroll
            for (int nt = 0; nt < NT; ++nt)
                *(f32x4*)(red + ((size_t)(mt*NT + nt))*256 + lane*4) = acc[mt][nt];
    }
    __syncthreads();
    if (wv == 1) {
        #pragma unroll
        for (int mt = 0; mt < 3; ++mt)
            #pragma unroll
            for (int nt = 0; nt < NT; ++nt) {
                f32x4* p = (f32x4*)(red + ((size_t)(mt*NT + nt))*256 + lane*4);
                *p = *p + acc[mt][nt];
            }
    }
    __syncthreads();
    if (wv == 0) {
        constexpr int OC = NT * 16;
        #pragma unroll
        for (int nt = 0; nt < NT; ++nt) {
            int oc = nt*16 + lr;
            float sc = scale[oc], bi = bias[oc];
            #pragma unroll
            for (int mt = 0; mt < 3; ++mt) {
                f32x4 a = acc[mt][nt] + *(const f32x4*)(red + ((size_t)(mt*NT + nt))*256 + lane*4);
                #pragma unroll
                for (int i = 0; i < 4; ++i) {
                    int s = mt*16 + kg*4 + i;
                    if (s < 36) {
                        float v = fmaxf(a[i]*sc + bi, 0.f);
                        short h, l; splith(v, h, l);
                        outH[(size_t)row*36*OC + s*OC + oc] = h;   // k = s*64+oc
                        outL[(size_t)row*36*OC + s*OC + oc] = l;
                    }
                }
            }
        }
    }
}

// ---------------- fc(2304->64) fp16-split MFMA (K-split over 4 waves) + LayerNorm + relu ----------------
// grid 384, block 256. Each block: 16 rows. A = catH (hi/lo, k = s*64+oc), B = fcB[o][k] hi/lo.
__global__ __launch_bounds__(256) void k_fc_mfma(
        const short* __restrict__ Ah, const short* __restrict__ Al,
        const short* __restrict__ Bh, const short* __restrict__ Bl,
        const float* __restrict__ fcb,
        const float* __restrict__ gamma, const float* __restrict__ beta,
        float* __restrict__ roi) {
    __shared__ float red[3 * 4 * 256];
    __shared__ float lnb[16][65];
    int tid = threadIdx.x;
    int wv = tid >> 6, lane = tid & 63;
    int lr = lane & 15, kg = lane >> 4;
    int row0 = blockIdx.x * 16;
    f32x4 acc[4] = {};
    for (int kk = 0; kk < 18; ++kk) {
        int k = (wv*18 + kk)*32 + kg*8;
        size_t ar = (size_t)(row0 + lr)*2304 + k;
        f16x8 ah = *(const f16x8*)(Ah + ar);
        f16x8 al = *(const f16x8*)(Al + ar);
        f16x8 bh[4], bl[4];
        #pragma unroll
        for (int nt = 0; nt < 4; ++nt) {
            size_t br = (size_t)(nt*16 + lr)*2304 + k;
            bh[nt] = *(const f16x8*)(Bh + br);
            bl[nt] = *(const f16x8*)(Bl + br);
        }
        // term-major: per-tile order hh->hl->lh preserved
        #pragma unroll
        for (int nt = 0; nt < 4; ++nt)
            acc[nt] = __builtin_amdgcn_mfma_f32_16x16x32_f16(ah, bh[nt], acc[nt], 0,0,0);
        #pragma unroll
        for (int nt = 0; nt < 4; ++nt)
            acc[nt] = __builtin_amdgcn_mfma_f32_16x16x32_f16(ah, bl[nt], acc[nt], 0,0,0);
        #pragma unroll
        for (int nt = 0; nt < 4; ++nt)
            acc[nt] = __builtin_amdgcn_mfma_f32_16x16x32_f16(al, bh[nt], acc[nt], 0,0,0);
    }
    if (wv > 0) {
        #pragma unroll
        for (int nt = 0; nt < 4; ++nt)
            *(f32x4*)(red + ((size_t)((wv-1)*4 + nt))*256 + lane*4) = acc[nt];
    }
    __syncthreads();
    if (wv == 0) {
        #pragma unroll
        for (int nt = 0; nt < 4; ++nt) {
            f32x4 a = acc[nt]
                    + *(const f32x4*)(red + ((size_t)(0*4 + nt))*256 + lane*4)
                    + *(const f32x4*)(red + ((size_t)(1*4 + nt))*256 + lane*4)
                    + *(const f32x4*)(red + ((size_t)(2*4 + nt))*256 + lane*4);
            #pragma unroll
            for (int i = 0; i < 4; ++i)
                lnb[kg*4 + i][nt*16 + lr] = a[i];
        }
    }
    __syncthreads();
    // LN: wave wv handles rows wv*4 .. wv*4+3; lane = output col
    #pragma unroll
    for (int rr = 0; rr < 4; ++rr) {
        int r = wv*4 + rr;
        float y = lnb[r][lane] + fcb[lane];
        float sum = y;
        #pragma unroll
        for (int off = 32; off > 0; off >>= 1) sum += __shfl_xor(sum, off);
        float mu = sum * (1.f/64.f);
        float d = y - mu;
        float vs = d * d;
        #pragma unroll
        for (int off = 32; off > 0; off >>= 1) vs += __shfl_xor(vs, off);
        float var = vs * (1.f/64.f);
        float outv = d * (1.0f / sqrtf(var + 1e-5f)) * gamma[lane] + beta[lane];
        roi[(size_t)(row0 + r)*64 + lane] = fmaxf(outv, 0.f);
    }
}

// ---------------- key/value maps at the 250 resize-nearest pixels (featT, coalesced) ----------------
__global__ __launch_bounds__(64) void k_keyval(const float* __restrict__ featT, int H, int W,
        const float* __restrict__ kw, const float* __restrict__ ks, const float* __restrict__ kb,
        const float* __restrict__ vw, const float* __restrict__ vb,
        float* __restrict__ keymap, float* __restrict__ valmap) {
    int site = blockIdx.x;
    int b = site / NPIX, n = site % NPIX;
    int r = n / 25, q = n % 25;
    int y = r * H / 10, x = q * W / 25;
    __shared__ float xv[64];
    int tid = threadIdx.x;
    xv[tid] = featT[((size_t)(b * H + y) * W + x) * 64 + tid];
    __syncthreads();
    float ak0 = 0.f, ak1 = 0.f, av0 = 0.f, av1 = 0.f;
    #pragma unroll 4
    for (int c = 0; c < 64; c += 2) {
        float f0 = xv[c], f1 = xv[c+1];
        ak0 += f0 * kw[tid*64 + c];
        ak1 += f1 * kw[tid*64 + c + 1];
        av0 += f0 * vw[tid*64 + c];
        av1 += f1 * vw[tid*64 + c + 1];
    }
    float ak = ak0 + ak1, av = av0 + av1;
    keymap[(size_t)(b*64 + tid) * NPIX + n] = fmaxf(ak * ks[tid] + kb[tid], 0.f);
    valmap[(size_t)(b*NPIX + n) * 64 + tid] = av + vb[tid];
}

// ---------------- attention (250 keys), roi updated in place ----------------
// QK: lane = key (4-acc ILP). PV: 4 waves split the 250 keys, LDS partial reduce.
__global__ __launch_bounds__(256) void k_attn(float* __restrict__ roi,
        const float* __restrict__ keymap, const float* __restrict__ valmap,
        const float* __restrict__ fqw, const float* __restrict__ fqb,
        const float* __restrict__ aws, const float* __restrict__ awb) {
    int rI = blockIdx.x;
    int b = rI / PPRI, p = rI % PPRI;
    __shared__ float q[64];
    __shared__ float sc[256];
    __shared__ float red[4];
    __shared__ float pv[4][64];
    int tid = threadIdx.x;
    if (tid < 64) q[tid] = fmaxf(roi[(size_t)rI*64 + tid] * fqw[p] + fqb[p], 0.f);
    __syncthreads();
    float s = -INFINITY;
    if (tid < NPIX) {
        const float* km = keymap + (size_t)b*64*NPIX + tid;
        float a0 = 0.f, a1 = 0.f, a2 = 0.f, a3 = 0.f;
        #pragma unroll 4
        for (int c = 0; c < 64; c += 4) {
            a0 += q[c  ] * km[(c  )*NPIX];
            a1 += q[c+1] * km[(c+1)*NPIX];
            a2 += q[c+2] * km[(c+2)*NPIX];
            a3 += q[c+3] * km[(c+3)*NPIX];
        }
        s = ((a0 + a1) + (a2 + a3)) * 0.125f;
    }
    float m = s;
    #pragma unroll
    for (int off = 32; off > 0; off >>= 1) m = fmaxf(m, __shfl_xor(m, off));
    if ((tid & 63) == 0) red[tid >> 6] = m;
    __syncthreads();
    m = fmaxf(fmaxf(red[0], red[1]), fmaxf(red[2], red[3]));
    __syncthreads();
    float e = (tid < NPIX) ? expf(s - m) : 0.f;
    sc[tid] = e;
    float su = e;
    #pragma unroll
    for (int off = 32; off > 0; off >>= 1) su += __shfl_xor(su, off);
    if ((tid & 63) == 0) red[tid >> 6] = su;
    __syncthreads();
    su = red[0] + red[1] + red[2] + red[3];
    float inv = 1.f / su;
    // PV: wave w accumulates keys [64w, min(250, 64w+64)) for channel c = tid&63
    int w = tid >> 6, c = tid & 63;
    int n0 = w * 64, n1 = min(NPIX, n0 + 64);
    const float* vm = valmap + (size_t)b*NPIX*64 + c;
    float b0 = 0.f, b1 = 0.f, b2 = 0.f, b3 = 0.f;
    int n = n0;
    for (; n + 3 < n1; n += 4) {
        b0 += sc[n  ] * vm[(size_t)(n  )*64];
        b1 += sc[n+1] * vm[(size_t)(n+1)*64];
        b2 += sc[n+2] * vm[(size_t)(n+2)*64];
        b3 += sc[n+3] * vm[(size_t)(n+3)*64];
    }
    for (; n < n1; ++n) b0 += sc[n] * vm[(size_t)n*64];
    pv[w][c] = (b0 + b1) + (b2 + b3);
    __syncthreads();
    if (tid < 64) {
        float acc = (pv[0][tid] + pv[1][tid]) + (pv[2][tid] + pv[3][tid]);
        size_t o = (size_t)rI*64 + tid;
        roi[o] = roi[o] + (acc * inv) * aws[p] + awb[p];
    }
}

// coalesced matvec, 4-acc ILP: out[tid] = sum_c v[c] * WT[c*ld + tid]
__device__ inline float dotT(const float* __restrict__ v, const float* __restrict__ wT, int ld) {
    float a0 = 0.f, a1 = 0.f, a2 = 0.f, a3 = 0.f;
    #pragma unroll 4
    for (int c = 0; c < 64; c += 4) {
        a0 += v[c  ] * wT[(c  )*ld];
        a1 += v[c+1] * wT[(c+1)*ld];
        a2 += v[c+2] * wT[(c+2)*ld];
        a3 += v[c+3] * wT[(c+3)*ld];
    }
    return (a0 + a1) + (a2 + a3);
}

// ---------------- heads: reg (+ cls at stage 2), geometry, prior update / output ----------------
__global__ __launch_bounds__(128) void k_head(int stage,
        float* __restrict__ p234g, float* __restrict__ pofm,
        const float* __restrict__ roi,
        const float* __restrict__ rw1T, const float* __restrict__ rb1,
        const float* __restrict__ rw2T, const float* __restrict__ rb2,
        const float* __restrict__ rhwT, const float* __restrict__ rhb,
        const float* __restrict__ cw1T, const float* __restrict__ cb1,
        const float* __restrict__ cw2T, const float* __restrict__ cb2,
        const float* __restrict__ chwT, const float* __restrict__ chb,
        float* __restrict__ out) {
    int rI = blockIdx.x;
    int b = rI / PPRI, p = rI % PPRI;
    int src = p * NB + b;                     // ff row scramble
    __shared__ float ff[64], h1[64], h2[64], rg[76];
    int tid = threadIdx.x;
    if (tid < 64) ff[tid] = roi[(size_t)src*64 + tid];
    __syncthreads();
    if (tid < 64) h1[tid] = fmaxf(dotT(ff, rw1T + tid, 64) + rb1[tid], 0.f);
    __syncthreads();
    if (tid < 64) h2[tid] = fmaxf(dotT(h1, rw2T + tid, 64) + rb2[tid], 0.f);
    __syncthreads();
    if (tid < 76) rg[tid] = dotT(h2, rhwT + tid, 76) + rhb[tid];
    __syncthreads();
    float* p234 = p234g + (size_t)rI * 3;
    float p2 = p234[0] + rg[0];
    float p3 = p234[1] + rg[1];
    float p4 = p234[2] + rg[2];
    float tanv = tanf(p4 * FPI + 1e-5f);
    if (stage < 2) {
        if (tid == 0) { p234[0] = p2; p234[1] = p3; p234[2] = p4; }
        if (tid < 36) {
            int k = (tid == 35) ? 71 : 2*tid;
            float prior_y = (float)(1.0 - (double)k / 71.0);
            float geom = (p3 * 799.0f + ((1.0f - prior_y - p2) * 320.0f) / tanv) / 799.0f;
            pofm[(size_t)rI * 36 + tid] = geom;
        }
    } else {
        if (tid < 64) h1[tid] = fmaxf(dotT(ff, cw1T + tid, 64) + cb1[tid], 0.f);
        __syncthreads();
        if (tid < 64) h2[tid] = fmaxf(dotT(h1, cw2T + tid, 64) + cb2[tid], 0.f);
        __syncthreads();
        float* ob = out + (size_t)rI * 78;
        if (tid < 2) ob[tid] = dotT(h2, chwT + tid, 2) + chb[tid];
        if (tid == 64) { ob[2] = p2; ob[3] = p3; ob[4] = p4; ob[5] = rg[3]; }
        if (tid < 72) {
            int k = tid;
            float prior_y = (float)(1.0 - (double)k / 71.0);
            float geom = (p3 * 799.0f + ((1.0f - prior_y - p2) * 320.0f) / tanv) / 799.0f;
            ob[6 + k] = geom + rg[4 + k];
        }
    }
}

// ---------------- final category + attribute heads ----------------
__global__ __launch_bounds__(64) void k_catattr(const float* __restrict__ roi,
        const float* __restrict__ cw1T, const float* __restrict__ cb1,
        const float* __restrict__ cw2T, const float* __restrict__ cb2,
        const float* __restrict__ protoNT,
        const float* __restrict__ aw1T, const float* __restrict__ ab1,
        const float* __restrict__ aw2T, const float* __restrict__ ab2,
        const float* __restrict__ ahwT, const float* __restrict__ ahb,
        float* __restrict__ out) {
    const size_t CAT_OFF = (size_t)BP * 78;
    const size_t ATTR_OFF = CAT_OFF + (size_t)BP * 15;
    int rI = blockIdx.x;
    int b = rI / PPRI, p = rI % PPRI;
    int src = p * NB + b;
    __shared__ float ff[64], h1[64], h2[64];
    int tid = threadIdx.x;
    ff[tid] = roi[(size_t)src*64 + tid];
    __syncthreads();
    h1[tid] = fmaxf(dotT(ff, cw1T + tid, 64) + cb1[tid], 0.f);
    __syncthreads();
    float v = fmaxf(dotT(h1, cw2T + tid, 64) + cb2[tid], 0.f);
    float ssq = v * v;
    #pragma unroll
    for (int off = 32; off > 0; off >>= 1) ssq += __shfl_xor(ssq, off);
    float nrm = fmaxf(sqrtf(ssq), 1e-12f);
    h2[tid] = v / nrm;
    __syncthreads();
    if (tid < 15) out[CAT_OFF + (size_t)rI*15 + tid] = dotT(h2, protoNT + tid, 15) * 20.0f;
    __syncthreads();
    h1[tid] = fmaxf(dotT(ff, aw1T + tid, 64) + ab1[tid], 0.f);
    __syncthreads();
    float va = fmaxf(dotT(h1, aw2T + tid, 64) + ab2[tid], 0.f);
    h2[tid] = va;
    __syncthreads();
    if (tid < 4) out[ATTR_OFF + (size_t)rI*4 + tid] = dotT(h2, ahwT + tid, 4) + ahb[tid];
}

extern "C" void kernel_launch(void* const* d_in, const int* in_sizes, int n_in,
                              void* d_out, int out_size, void* d_ws, size_t ws_size,
                              hipStream_t stream) {
    (void)in_sizes; (void)n_in; (void)out_size; (void)ws_size;
    const float* feat_s8   = (const float*)d_in[0];
    const float* feat_s16  = (const float*)d_in[1];
    const float* feat_s32  = (const float*)d_in[2];
    const float* rg_conv_w     = (const float*)d_in[3];
    const float* rg_conv_scale = (const float*)d_in[4];
    const float* rg_conv_bias  = (const float*)d_in[5];
    const float* catconv_w[3]  = {(const float*)d_in[6], (const float*)d_in[7], (const float*)d_in[8]};
    const float* catconv_scale = (const float*)d_in[9];
    const float* catconv_bias  = (const float*)d_in[10];
    const float* fc_w = (const float*)d_in[11];
    const float* fc_b = (const float*)d_in[12];
    const float* ln_gamma = (const float*)d_in[13];
    const float* ln_beta  = (const float*)d_in[14];
    const float* fkey_w = (const float*)d_in[15];
    const float* fkey_scale = (const float*)d_in[16];
    const float* fkey_bias  = (const float*)d_in[17];
    const float* fvalue_w = (const float*)d_in[18];
    const float* fvalue_b = (const float*)d_in[19];
    const float* fquery_w = (const float*)d_in[20];
    const float* fquery_b = (const float*)d_in[21];
    const float* attn_w_scale = (const float*)d_in[22];
    const float* attn_w_bias  = (const float*)d_in[23];
    const float* cls_w1 = (const float*)d_in[24];
    const float* cls_b1 = (const float*)d_in[25];
    const float* cls_w2 = (const float*)d_in[26];
    const float* cls_b2 = (const float*)d_in[27];
    const float* reg_w1 = (const float*)d_in[28];
    const float* reg_b1 = (const float*)d_in[29];
    const float* reg_w2 = (const float*)d_in[30];
    const float* reg_b2 = (const float*)d_in[31];
    const float* cls_head_w = (const float*)d_in[32];
    const float* cls_head_b = (const float*)d_in[33];
    const float* reg_head_w = (const float*)d_in[34];
    const float* reg_head_b = (const float*)d_in[35];
    const float* cat_w1 = (const float*)d_in[36];
    const float* cat_b1 = (const float*)d_in[37];
    const float* cat_w2 = (const float*)d_in[38];
    const float* cat_b2 = (const float*)d_in[39];
    const float* prototypes = (const float*)d_in[40];
    const float* attr_w1 = (const float*)d_in[41];
    const float* attr_b1 = (const float*)d_in[42];
    const float* attr_w2 = (const float*)d_in[43];
    const float* attr_b2 = (const float*)d_in[44];
    const float* attr_head_w = (const float*)d_in[45];
    const float* attr_head_b = (const float*)d_in[46];

    float* ws = (float*)d_ws;
    // fp32 region (float offsets, all 16B-aligned)
    float* pofm   = ws;                        // 221,184
    float* p234   = ws + 221184;               // 18,432
    short* fcBh   = (short*)(ws + 240576);     // 147,456 sh
    short* fcBl   = (short*)(ws + 314304);     // 147,456 sh
    float* roi    = ws + 388032;               // 393,216
    float* keymap = ws + 781248;               // 512,000
    float* valmap = ws + 1293248;              // 512,000
    short* catHh  = (short*)(ws + 1805248);    // 14,155,776 sh
    short* catHl  = (short*)(ws + 8883136);    // 14,155,776 sh
    float* featT  = ws + 15961024;             // 8,192,000 fp32 (max 32*4000*64)
    // fp16 buffers (short*, offsets in floats)
    short* rgCh   = (short*)(ws + 30116800);   // 31,850,496 sh (3 stages)
    short* rgCl   = (short*)(ws + 46042048);   // 31,850,496 sh
    short* rgWh   = (short*)(ws + 61967296);   // 82,944 sh
    short* rgWl   = (short*)(ws + 62008768);   // 82,944 sh
    short* catWh  = (short*)(ws + 62050240);   // 184,320 sh
    short* catWl  = (short*)(ws + 62142400);   // 184,320 sh
    // transposed head weights (fp32)
    float* hT      = ws + 62234560;            // 32,768 (8 x 64x64, [c][o])
    float* rhwT    = ws + 62267328;            // 4,864
    float* chwT    = ws + 62272192;            // 128
    float* ahwT    = ws + 62272320;            // 256
    float* protoNT = ws + 62272576;            // 960

    float* out = (float*)d_out;

    k_init<<<864, 256, 0, stream>>>(pofm, p234, fcBh, fcBl, fc_w, prototypes,
                                    rgWh, rgWl, rg_conv_w, catWh, catWl,
                                    catconv_w[0], catconv_w[1], catconv_w[2],
                                    hT, rhwT, chwT, ahwT, protoNT,
                                    reg_w1, reg_w2, cls_w1, cls_w2,
                                    cat_w1, cat_w2, attr_w1, attr_w2,
                                    reg_head_w, cls_head_w, attr_head_w);

    const float* feats[3] = {feat_s32, feat_s16, feat_s8};
    const int Hs[3] = {10, 20, 40}, Wstg[3] = {25, 50, 100};
    const int catbase[3] = {0, 36864, 92160};

    for (int st = 0; st < 3; ++st) {
        int HW = Hs[st] * Wstg[st];
        k_transpose<<<dim3((HW + 63)/64, NB), 256, 0, stream>>>(feats[st], featT, HW);
        // fused gridsample + rg conv (64 -> 48): fp16-split for st 0/1, fp16-single for st 2
        if (st < 2)
            k_rgfused<true><<<BP, 192, 0, stream>>>(featT, Hs[st], Wstg[st], pofm,
                                                    rgWh + st*27648, rgWl + st*27648,
                                                    rg_conv_scale + st*48, rg_conv_bias + st*48,
                                                    rgCh + (size_t)st*BP*1728, rgCl + (size_t)st*BP*1728);
        else
            k_rgfused<false><<<BP, 192, 0, stream>>>(featT, Hs[st], Wstg[st], pofm,
                                                     rgWh + st*27648, rgWl + st*27648,
                                                     rg_conv_scale + st*48, rg_conv_bias + st*48,
                                                     rgCh + (size_t)st*BP*1728, rgCl + (size_t)st*BP*1728);
        // cat conv: 48*(st+1) -> 64, fp16 hi/lo output (k = s*64+oc)
        if (st == 0)
            k_catconv<2,4,48,80,48,true><<<BP, 192, 0, stream>>>(
                    rgCh, rgCl, catWh + catbase[0], catWl + catbase[0],
                    catconv_scale, catconv_bias, catHh, catHl);
        else if (st == 1)
            k_catconv<3,4,48,112,96,true><<<BP, 192, 0, stream>>>(
                    rgCh, rgCl, catWh + catbase[1], catWl + catbase[1],
                    catconv_scale + 64, catconv_bias + 64, catHh, catHl);
        else
            k_catconv<5,4,48,176,144,false><<<BP, 192, 0, stream>>>(
                    rgCh, rgCl, catWh + catbase[2], catWl + catbase[2],
                    catconv_scale + 128, catconv_bias + 128, catHh, catHl);
        k_fc_mfma<<<384, 256, 0, stream>>>(catHh, catHl, fcBh, fcBl,
                                           fc_b, ln_gamma, ln_beta, roi);
        k_keyval<<<NB*NPIX, 64, 0, stream>>>(featT, Hs[st], Wstg[st],
                                             fkey_w, fkey_scale, fkey_bias,
                                             fvalue_w, fvalue_b, keymap, valmap);
        k_attn<<<BP, 256, 0, stream>>>(roi, keymap, valmap, fquery_w, fquery_b,
                                       attn_w_scale, attn_w_bias);
        k_head<<<BP, 128, 0, stream>>>(st, p234, pofm, roi,
                                       hT + 0, reg_b1, hT + 4096, reg_b2, rhwT, reg_head_b,
                                       hT + 8192, cls_b1, hT + 12288, cls_b2, chwT, cls_head_b,
                                       out);
    }
    k_catattr<<<BP, 64, 0, stream>>>(roi, hT + 16384, cat_b1, hT + 20480, cat_b2, protoNT,
                                     hT + 24576, attr_b1, hT + 28672, attr_b2,
                                     ahwT, attr_head_b, out);
}